// Round 1
// baseline (100.329 us; speedup 1.0000x reference)
//
#include <hip/hip_runtime.h>
#include <cmath>

#define N_TOKENS 65536
#define DIM 256
#define NCLUST 128
#define DOUT 256

#define TM 64   // tokens per block
#define KB 64   // k chunk
#define AP 68   // A tile row pitch (pad keeps float4 alignment, conflict-free)

// ---------------- kernel 1: tiny precompute -----------------------------
// pc[n][o] = sum_d centers[n][d] * proj_w[o][d] + proj_b[o]
// csq[n]   = sum_d centers[n][d]^2
// ct[k][n] = centers[n][k]   (transpose, so kernel 2 stages B conflict-free)
__global__ __launch_bounds__(256) void precompute_kernel(
    const float* __restrict__ centers,
    const float* __restrict__ proj_w,
    const float* __restrict__ proj_b,
    float* __restrict__ pc,
    float* __restrict__ csq,
    float* __restrict__ ct)
{
    __shared__ float cl[DIM];
    __shared__ float red[4];
    const int n = blockIdx.x;
    const int tid = threadIdx.x;

    float cv = centers[n * DIM + tid];
    cl[tid] = cv;
    ct[(size_t)tid * NCLUST + n] = cv;

    float s = cv * cv;
    #pragma unroll
    for (int off = 32; off >= 1; off >>= 1)
        s += __shfl_down(s, off, 64);
    if ((tid & 63) == 0) red[tid >> 6] = s;
    __syncthreads();
    if (tid == 0) csq[n] = (red[0] + red[1]) + (red[2] + red[3]);

    float acc = 0.f;
    const float* wrow = proj_w + (size_t)tid * DIM;
    #pragma unroll 4
    for (int d = 0; d < DIM; d += 4) {
        float4 w = *(const float4*)(wrow + d);
        acc = fmaf(w.x, cl[d + 0], acc);
        acc = fmaf(w.y, cl[d + 1], acc);
        acc = fmaf(w.z, cl[d + 2], acc);
        acc = fmaf(w.w, cl[d + 3], acc);
    }
    pc[(size_t)n * DOUT + tid] = acc + proj_b[tid];
}

// ---------------- kernel 2: scores GEMM + argmin + gather ---------------
__global__ __launch_bounds__(256) void cluster_kernel(
    const float* __restrict__ x,
    const float* __restrict__ ct,    // [DIM][NCLUST] transposed centers
    const float* __restrict__ pc,    // [NCLUST][DOUT] projected centers
    const float* __restrict__ csq,   // [NCLUST]
    const unsigned char* __restrict__ masks,
    float* __restrict__ out)
{
    __shared__ float As[TM * AP];        // [t][k] pitch 68
    __shared__ float Bs[KB * NCLUST];    // [k][n] pitch 128
    __shared__ float sc[NCLUST];
    __shared__ int sbest[TM];

    const int tid = threadIdx.x;
    const int tx = tid & 15;     // cluster group: clusters tx*8 .. tx*8+7
    const int ty = tid >> 4;     // token group: tokens ty*4 .. ty*4+3
    const int t0 = blockIdx.x * TM;

    if (tid < NCLUST) sc[tid] = csq[tid];

    float acc[4][8];
    float xsq[4];
    #pragma unroll
    for (int i = 0; i < 4; ++i) {
        xsq[i] = 0.f;
        #pragma unroll
        for (int j = 0; j < 8; ++j) acc[i][j] = 0.f;
    }

    for (int kc = 0; kc < DIM; kc += KB) {
        // stage A: x[t0+t][kc+k] -> As[t][k]   (coalesced, conflict-free)
        #pragma unroll
        for (int it = 0; it < 4; ++it) {
            int idx = it * 256 + tid;
            int t = idx >> 4;
            int k4 = idx & 15;
            float4 v = *(const float4*)(x + (size_t)(t0 + t) * DIM + kc + k4 * 4);
            *(float4*)&As[t * AP + k4 * 4] = v;
        }
        // stage B: ct[kc+k][n] -> Bs[k][n]   (coalesced, conflict-free)
        #pragma unroll
        for (int it = 0; it < 8; ++it) {
            int idx = it * 256 + tid;
            int k = idx >> 5;
            int g = idx & 31;
            float4 v = *(const float4*)(ct + (size_t)(kc + k) * NCLUST + g * 4);
            *(float4*)&Bs[k * NCLUST + g * 4] = v;
        }
        __syncthreads();

        #pragma unroll
        for (int k = 0; k < KB; k += 4) {
            float a[4][4];
            #pragma unroll
            for (int i = 0; i < 4; ++i)
                *(float4*)a[i] = *(const float4*)&As[(ty * 4 + i) * AP + k];
            #pragma unroll
            for (int kk = 0; kk < 4; ++kk) {
                float b[8];
                *(float4*)&b[0] = *(const float4*)&Bs[(k + kk) * NCLUST + tx * 8];
                *(float4*)&b[4] = *(const float4*)&Bs[(k + kk) * NCLUST + tx * 8 + 4];
                #pragma unroll
                for (int i = 0; i < 4; ++i) {
                    float av = a[i][kk];
                    xsq[i] = fmaf(av, av, xsq[i]);
                    #pragma unroll
                    for (int j = 0; j < 8; ++j)
                        acc[i][j] = fmaf(av, b[j], acc[i][j]);
                }
            }
        }
        __syncthreads();
    }

    // per-token argmin over 128 clusters (local 8, then across 16 lanes)
    #pragma unroll
    for (int i = 0; i < 4; ++i) {
        float bv = INFINITY;
        int bi = 0x7FFFFFFF;
        #pragma unroll
        for (int j = 0; j < 8; ++j) {
            int ci = tx * 8 + j;
            float d2 = fmaf(-2.f, acc[i][j], xsq[i]) + sc[ci];
            if (d2 < bv) { bv = d2; bi = ci; }
        }
        #pragma unroll
        for (int m = 1; m < 16; m <<= 1) {
            float ov = __shfl_xor(bv, m, 64);
            int oi = __shfl_xor(bi, m, 64);
            if (ov < bv || (ov == bv && oi < bi)) { bv = ov; bi = oi; }
        }
        if (tx == 0) sbest[ty * 4 + i] = bi;
    }
    __syncthreads();

    // epilogue: out[t][:] = pc[best[t]][:] * keep
    #pragma unroll
    for (int it = 0; it < 16; ++it) {
        int idx = it * 256 + tid;
        int t = idx >> 6;
        int f4 = idx & 63;
        int best = sbest[t];
        float mval = masks[t0 + t] ? 0.f : 1.f;
        float4 v = *(const float4*)(pc + (size_t)best * DOUT + f4 * 4);
        v.x *= mval; v.y *= mval; v.z *= mval; v.w *= mval;
        *(float4*)(out + (size_t)(t0 + t) * DOUT + f4 * 4) = v;
    }
}

extern "C" void kernel_launch(void* const* d_in, const int* in_sizes, int n_in,
                              void* d_out, int out_size, void* d_ws, size_t ws_size,
                              hipStream_t stream) {
    const float* x = (const float*)d_in[0];
    const float* centers = (const float*)d_in[1];
    const float* proj_w = (const float*)d_in[2];
    const float* proj_b = (const float*)d_in[3];
    const unsigned char* masks = (const unsigned char*)d_in[4];
    float* out = (float*)d_out;

    float* ws = (float*)d_ws;
    float* pc = ws;                              // 128*256
    float* csq = ws + NCLUST * DOUT;             // 128
    float* ct = ws + NCLUST * DOUT + NCLUST;     // 256*128

    precompute_kernel<<<NCLUST, 256, 0, stream>>>(centers, proj_w, proj_b, pc, csq, ct);
    cluster_kernel<<<N_TOKENS / TM, 256, 0, stream>>>(x, ct, pc, csq, masks, out);
}

// Round 3
// 91.699 us; speedup vs baseline: 1.0941x; 1.0941x over previous
//
#include <hip/hip_runtime.h>
#include <cmath>

#define N_TOKENS 65536
#define DIM 256
#define NCLUST 128
#define DOUT 256

#define BM 64    // tokens per block
#define BKC 64   // k chunk
#define EPS 2e-3f

typedef __bf16 bf16_t;
typedef bf16_t bf16x8 __attribute__((ext_vector_type(8)));
typedef float f32x4 __attribute__((ext_vector_type(4)));

__device__ inline void split3(float x, bf16_t& h, bf16_t& m, bf16_t& l) {
    h = (bf16_t)x;
    float r = x - (float)h;       // exact
    m = (bf16_t)r;
    float r2 = r - (float)m;      // exact
    l = (bf16_t)r2;
}

// ---------------- kernel 1: precompute -----------------------------
// csq[n] (round-1 float butterfly — must match the arithmetic that passed),
// pc[n][o] = centers@proj_w^T + b, 3-way bf16 split planes of centers.
__global__ __launch_bounds__(256) void precompute_kernel(
    const float* __restrict__ centers,
    const float* __restrict__ proj_w,
    const float* __restrict__ proj_b,
    float* __restrict__ pc,
    float* __restrict__ csq,
    bf16_t* __restrict__ cbh,
    bf16_t* __restrict__ cbm,
    bf16_t* __restrict__ cbl)
{
    __shared__ float cl[DIM];
    __shared__ float red[4];
    const int n = blockIdx.x;
    const int tid = threadIdx.x;

    float cv = centers[n * DIM + tid];
    cl[tid] = cv;

    bf16_t h, m, l;
    split3(cv, h, m, l);
    cbh[(size_t)n * DIM + tid] = h;
    cbm[(size_t)n * DIM + tid] = m;
    cbl[(size_t)n * DIM + tid] = l;

    float s = cv * cv;
    #pragma unroll
    for (int off = 32; off >= 1; off >>= 1)
        s += __shfl_down(s, off, 64);
    if ((tid & 63) == 0) red[tid >> 6] = s;
    __syncthreads();
    if (tid == 0) csq[n] = (red[0] + red[1]) + (red[2] + red[3]);

    float acc = 0.f;
    const float* wrow = proj_w + (size_t)tid * DIM;
    #pragma unroll 4
    for (int d = 0; d < DIM; d += 4) {
        float4 w = *(const float4*)(wrow + d);
        acc = fmaf(w.x, cl[d + 0], acc);
        acc = fmaf(w.y, cl[d + 1], acc);
        acc = fmaf(w.z, cl[d + 2], acc);
        acc = fmaf(w.w, cl[d + 3], acc);
    }
    pc[(size_t)n * DOUT + tid] = acc + proj_b[tid];
}

// ---------------- kernel 2: MFMA scores + filtered argmin + gather ------
__global__ __launch_bounds__(256) void cluster_mfma_kernel(
    const float* __restrict__ x,
    const float* __restrict__ centers,
    const bf16_t* __restrict__ cbh,
    const bf16_t* __restrict__ cbm,
    const bf16_t* __restrict__ cbl,
    const float* __restrict__ csq,
    const float* __restrict__ pc,
    const unsigned char* __restrict__ masks,
    float* __restrict__ out)
{
    __shared__ bf16_t Ah[BM * BKC];
    __shared__ bf16_t Am[BM * BKC];
    __shared__ bf16_t Al[BM * BKC];
    __shared__ float scs[NCLUST];
    __shared__ float sminv[2][BM];
    __shared__ int   smini[2][BM];
    __shared__ float sminT[BM];
    __shared__ int   scnt[BM];
    __shared__ int   sbest[BM];

    const int tid = threadIdx.x;
    const int lane = tid & 63;
    const int wid = tid >> 6;
    const int waveM = wid & 1;    // token half: waveM*32
    const int waveN = wid >> 1;   // cluster half: waveN*64
    const int lr = lane & 15;
    const int lg = lane >> 4;
    const int t0 = blockIdx.x * BM;

    if (tid < NCLUST) scs[tid] = csq[tid];

    f32x4 acc[2][4];
    #pragma unroll
    for (int mr = 0; mr < 2; ++mr)
        #pragma unroll
        for (int nr = 0; nr < 4; ++nr)
            acc[mr][nr] = (f32x4){0.f, 0.f, 0.f, 0.f};

    for (int kc = 0; kc < DIM; kc += BKC) {
        // ---- stage A: x -> 3 bf16 planes in LDS (XOR-swizzled c8) ----
        #pragma unroll
        for (int it = 0; it < 2; ++it) {
            int o = it * 256 + tid;
            int row = o >> 3;
            int c8 = o & 7;
            const float* src = x + (size_t)(t0 + row) * DIM + kc + c8 * 8;
            float4 v0 = *(const float4*)src;
            float4 v1 = *(const float4*)(src + 4);
            float xv[8] = {v0.x, v0.y, v0.z, v0.w, v1.x, v1.y, v1.z, v1.w};
            bf16x8 h8, m8, l8;
            #pragma unroll
            for (int e = 0; e < 8; ++e) {
                bf16_t h, m, l;
                split3(xv[e], h, m, l);
                h8[e] = h; m8[e] = m; l8[e] = l;
            }
            int base = row * BKC + ((c8 ^ (row & 7)) << 3);
            *(bf16x8*)&Ah[base] = h8;
            *(bf16x8*)&Am[base] = m8;
            *(bf16x8*)&Al[base] = l8;
        }
        __syncthreads();

        #pragma unroll
        for (int ks = 0; ks < 2; ++ks) {
            bf16x8 ah[2], am[2], al[2];
            #pragma unroll
            for (int mr = 0; mr < 2; ++mr) {
                int r = waveM * 32 + mr * 16 + lr;
                int c8r = ks * 4 + lg;
                int idx = r * BKC + ((c8r ^ (r & 7)) << 3);
                ah[mr] = *(const bf16x8*)&Ah[idx];
                am[mr] = *(const bf16x8*)&Am[idx];
                al[mr] = *(const bf16x8*)&Al[idx];
            }
            bf16x8 bh[4], bm[4], bl[4];
            int koff = kc + ks * 32 + lg * 8;
            #pragma unroll
            for (int nr = 0; nr < 4; ++nr) {
                int c = waveN * 64 + nr * 16 + lr;
                size_t off = (size_t)c * DIM + koff;
                bh[nr] = *(const bf16x8*)(cbh + off);
                bm[nr] = *(const bf16x8*)(cbm + off);
                bl[nr] = *(const bf16x8*)(cbl + off);
            }
            #pragma unroll
            for (int mr = 0; mr < 2; ++mr) {
                #pragma unroll
                for (int nr = 0; nr < 4; ++nr) {
                    f32x4 c = acc[mr][nr];
                    c = __builtin_amdgcn_mfma_f32_16x16x32_bf16(al[mr], bh[nr], c, 0, 0, 0);
                    c = __builtin_amdgcn_mfma_f32_16x16x32_bf16(ah[mr], bl[nr], c, 0, 0, 0);
                    c = __builtin_amdgcn_mfma_f32_16x16x32_bf16(am[mr], bm[nr], c, 0, 0, 0);
                    c = __builtin_amdgcn_mfma_f32_16x16x32_bf16(am[mr], bh[nr], c, 0, 0, 0);
                    c = __builtin_amdgcn_mfma_f32_16x16x32_bf16(ah[mr], bm[nr], c, 0, 0, 0);
                    c = __builtin_amdgcn_mfma_f32_16x16x32_bf16(ah[mr], bh[nr], c, 0, 0, 0);
                    acc[mr][nr] = c;
                }
            }
        }
        __syncthreads();
    }

    // ---- pass 1: approx argmin (score = csq - 2*dot), per half ----
    // C layout: col(cluster) = lane&15, row(token) = (lane>>4)*4 + reg
    #pragma unroll
    for (int mr = 0; mr < 2; ++mr) {
        #pragma unroll
        for (int reg = 0; reg < 4; ++reg) {
            float bv = INFINITY;
            int bi = 0;
            #pragma unroll
            for (int nr = 0; nr < 4; ++nr) {
                int c = waveN * 64 + nr * 16 + lr;
                float v = fmaf(-2.f, acc[mr][nr][reg], scs[c]);
                if (v < bv) { bv = v; bi = c; }
            }
            #pragma unroll
            for (int msk = 1; msk < 16; msk <<= 1) {
                float ov = __shfl_xor(bv, msk, 64);
                int oi = __shfl_xor(bi, msk, 64);
                if (ov < bv || (ov == bv && oi < bi)) { bv = ov; bi = oi; }
            }
            if (lr == 0) {
                int t = waveM * 32 + mr * 16 + lg * 4 + reg;
                sminv[waveN][t] = bv;
                smini[waveN][t] = bi;
            }
        }
    }
    __syncthreads();
    if (tid < BM) {
        float v0 = sminv[0][tid], v1 = sminv[1][tid];
        sminT[tid] = fminf(v0, v1);
        sbest[tid] = (v1 < v0) ? smini[1][tid] : smini[0][tid];
        scnt[tid] = 0;
    }
    __syncthreads();

    // ---- pass 2: count candidates within EPS of the min ----
    #pragma unroll
    for (int mr = 0; mr < 2; ++mr) {
        #pragma unroll
        for (int reg = 0; reg < 4; ++reg) {
            int t = waveM * 32 + mr * 16 + lg * 4 + reg;
            float thr = sminT[t] + EPS;
            int cnt = 0;
            #pragma unroll
            for (int nr = 0; nr < 4; ++nr) {
                int c = waveN * 64 + nr * 16 + lr;
                float v = fmaf(-2.f, acc[mr][nr][reg], scs[c]);
                cnt += (v <= thr) ? 1 : 0;
            }
            if (cnt > 0) atomicAdd(&scnt[t], cnt);
        }
    }
    __syncthreads();

    // ---- pass 3: exact fp32 recheck for near-tie tokens (rare) ----
    // Reproduces round-1 arithmetic bitwise: sequential-k fmaf dot & xsq,
    // d2 = fmaf(-2,dot,xsq) + csq, lexicographic (value,idx) min.
    for (int tt = 0; tt < 16; ++tt) {
        int t = wid * 16 + tt;
        if (scnt[t] < 2) continue;   // wave-uniform
        const float4* xr = (const float4*)(x + (size_t)(t0 + t) * DIM);
        const float4* c0 = (const float4*)(centers + (size_t)(2 * lane) * DIM);
        const float4* c1 = (const float4*)(centers + (size_t)(2 * lane + 1) * DIM);
        float xs = 0.f, d0 = 0.f, d1 = 0.f;
        #pragma unroll 4
        for (int k4 = 0; k4 < 64; ++k4) {
            float4 xv = xr[k4];
            float4 a = c0[k4];
            float4 b = c1[k4];
            xs = fmaf(xv.x, xv.x, xs); d0 = fmaf(xv.x, a.x, d0); d1 = fmaf(xv.x, b.x, d1);
            xs = fmaf(xv.y, xv.y, xs); d0 = fmaf(xv.y, a.y, d0); d1 = fmaf(xv.y, b.y, d1);
            xs = fmaf(xv.z, xv.z, xs); d0 = fmaf(xv.z, a.z, d0); d1 = fmaf(xv.z, b.z, d1);
            xs = fmaf(xv.w, xv.w, xs); d0 = fmaf(xv.w, a.w, d0); d1 = fmaf(xv.w, b.w, d1);
        }
        float s0 = fmaf(-2.f, d0, xs) + scs[2 * lane];
        float s1 = fmaf(-2.f, d1, xs) + scs[2 * lane + 1];
        float bv = s0;
        int bi = 2 * lane;
        if (s1 < bv) { bv = s1; bi = 2 * lane + 1; }
        #pragma unroll
        for (int msk = 1; msk < 64; msk <<= 1) {
            float ov = __shfl_xor(bv, msk, 64);
            int oi = __shfl_xor(bi, msk, 64);
            if (ov < bv || (ov == bv && oi < bi)) { bv = ov; bi = oi; }
        }
        if (lane == 0) sbest[t] = bi;
    }
    __syncthreads();

    // ---- epilogue: out[t][:] = pc[best[t]][:] * keep ----
    #pragma unroll
    for (int it = 0; it < 16; ++it) {
        int idx = it * 256 + tid;
        int t = idx >> 6;
        int f4 = idx & 63;
        int best = sbest[t];
        float mval = masks[t0 + t] ? 0.f : 1.f;
        float4 v = *(const float4*)(pc + (size_t)best * DOUT + f4 * 4);
        v.x *= mval; v.y *= mval; v.z *= mval; v.w *= mval;
        *(float4*)(out + (size_t)(t0 + t) * DIM + f4 * 4) = v;
    }
}

extern "C" void kernel_launch(void* const* d_in, const int* in_sizes, int n_in,
                              void* d_out, int out_size, void* d_ws, size_t ws_size,
                              hipStream_t stream) {
    const float* x = (const float*)d_in[0];
    const float* centers = (const float*)d_in[1];
    const float* proj_w = (const float*)d_in[2];
    const float* proj_b = (const float*)d_in[3];
    const unsigned char* masks = (const unsigned char*)d_in[4];
    float* out = (float*)d_out;

    char* ws = (char*)d_ws;
    float* pc   = (float*)(ws);                         // 131072 B
    float* csq  = (float*)(ws + 131072);                // 512 B
    bf16_t* cbh = (bf16_t*)(ws + 131584);               // 65536 B
    bf16_t* cbm = (bf16_t*)(ws + 131584 + 65536);
    bf16_t* cbl = (bf16_t*)(ws + 131584 + 131072);

    precompute_kernel<<<NCLUST, 256, 0, stream>>>(centers, proj_w, proj_b,
                                                  pc, csq, cbh, cbm, cbl);
    cluster_mfma_kernel<<<N_TOKENS / BM, 256, 0, stream>>>(x, centers, cbh, cbm, cbl,
                                                           csq, pc, masks, out);
}